// Round 10
// baseline (29.743 us; speedup 1.0000x reference)
//
#include <hip/hip_runtime.h>

#define BB 32
#define CC 384
#define TP 512
#define TF 2048

typedef float f32x4 __attribute__((ext_vector_type(4)));

__device__ __forceinline__ int imax(int a, int b) { return a > b ? a : b; }
__device__ __forceinline__ int imin(int a, int b) { return a < b ? a : b; }

// One kernel, flat grid of 1024 blocks, 256 threads.
// R10 = R9 with ONE change: plain (cached) stores for `out` instead of
// nontemporal. Theory: nt stores bypass L2 write-combining and cap the write
// path (~4.35 TB/s observed, invariant to all 9 rounds of layout changes);
// cached stores coalesce in L2 and drain at fill-kernel rates (6.9 TB/s).
// Type map (3 stream + 1 GEMV per CU under both dispatch models):
//   k = lid>>8, c = lid&255, m = (k + 4 - (c&3)) & 3;  m==0 -> GEMV.
//  stream: 16 c-rows x 2048 frames of out; wave-shuffle scan; direct global
//          gather of x (no LDS staging); float4 stores (1KB/wave-instr).
//  GEMV  : phone-space GEMV (y kept in LDS) + ldp + frame preds for this
//          block's contiguous frame window; jj==7 also writes the tail.
__global__ __launch_bounds__(256, 4) void mono_kernel(
    const float* __restrict__ x, const float* __restrict__ phone_mask,
    const float* __restrict__ frame_mask, const int* __restrict__ duration,
    const float* __restrict__ log_cf0, const float* __restrict__ energy,
    const float* __restrict__ dur_w, const float* __restrict__ dur_b,
    const float* __restrict__ pitch_w, const float* __restrict__ pitch_b,
    const float* __restrict__ pemb_w, const float* __restrict__ pemb_b,
    const float* __restrict__ enp_w, const float* __restrict__ enp_b,
    const float* __restrict__ eemb_w, const float* __restrict__ eemb_b,
    float* __restrict__ out, float* __restrict__ ldp, float* __restrict__ lcp,
    float* __restrict__ vup, float* __restrict__ epp) {
    int lid = blockIdx.x;        // 0..1023
    int k = lid >> 8;            // 0..3 (co-residency wave)
    int c = lid & 255;           // CU slot
    int b = c >> 3;              // 0..31
    int sl = c & 7;              // XCD slot 0..7
    int m = (k + 4 - (c & 3)) & 3;  // 0 -> GEMV, 1..3 -> stream
    int tid = threadIdx.x;
    int lane = tid & 63;
    int wv = tid >> 6;  // 0..3
    const float* xb = x + (size_t)b * CC * TP;

    if (m != 0) {
        // ---------------- stream block ----------------
        int j = sl + 8 * (m - 1);   // 0..23
        __shared__ short po16[TF];  // 4 KB frame->phone
        __shared__ float pm_s[TP];  // 2 KB phone_mask row
        __shared__ int wsum[4];     // per-wave scan totals
        int c0 = __builtin_amdgcn_readfirstlane(j * 16);

        // ---- early independent loads (latency hides under scan) ----
        const float* fm_b = frame_mask + (size_t)b * TF;
        const float* lc_b = log_cf0 + (size_t)b * TF;
        const float* en_b = energy + (size_t)b * TF;
        float fmv[8], lcv[8], env[8];
#pragma unroll
        for (int q = 0; q < 2; ++q) {
            int f = q * 1024 + 4 * tid;
            float4 fm4 = *(const float4*)(fm_b + f);
            float4 lc4 = *(const float4*)(lc_b + f);
            float4 en4 = *(const float4*)(en_b + f);
            fmv[4 * q + 0] = fm4.x; fmv[4 * q + 1] = fm4.y; fmv[4 * q + 2] = fm4.z; fmv[4 * q + 3] = fm4.w;
            lcv[4 * q + 0] = lc4.x; lcv[4 * q + 1] = lc4.y; lcv[4 * q + 2] = lc4.z; lcv[4 * q + 3] = lc4.w;
            env[4 * q + 0] = en4.x; env[4 * q + 1] = en4.y; env[4 * q + 2] = en4.z; env[4 * q + 3] = en4.w;
        }
        pm_s[tid] = phone_mask[b * TP + tid];
        pm_s[tid + 256] = phone_mask[b * TP + tid + 256];
        int2 d01 = *(const int2*)(duration + b * TP + 2 * tid);
        int d0 = d01.x, d1 = d01.y;
#pragma unroll
        for (int h = 0; h < 4; ++h) ((int*)po16)[tid + 256 * h] = -1;  // two -1 shorts

        // ---- wave-shuffle inclusive scan of pair sums ----
        int s = d0 + d1;
        int v = s;
#pragma unroll
        for (int off = 1; off < 64; off <<= 1) {
            int t = __shfl_up(v, off, 64);
            if (lane >= off) v += t;
        }
        if (lane == 63) wsum[wv] = v;
        __syncthreads();  // wsum + po16 init + pm_s ready
        int base = 0;
#pragma unroll
        for (int w = 0; w < 4; ++w) base += (w < wv) ? wsum[w] : 0;
        int excl = base + v - s;

        int e0 = imin(excl + d0, TF);
        int e1 = imin(excl + d0 + d1, TF);
        for (int f = imin(excl, TF); f < e0; ++f) po16[f] = (short)(2 * tid);
        for (int f = e0; f < e1; ++f) po16[f] = (short)(2 * tid + 1);
        __syncthreads();

        // ---- po16-dependent register cache: gather index + combined mask ----
        int pcl[8];
        float xm[8];
#pragma unroll
        for (int q = 0; q < 2; ++q) {
            short4 p4 = *(const short4*)(po16 + q * 1024 + 4 * tid);
            short pk[4] = {p4.x, p4.y, p4.z, p4.w};
#pragma unroll
            for (int kk = 0; kk < 4; ++kk) {
                int p = pk[kk];
                int pc = imax(p, 0);
                pcl[4 * q + kk] = pc;
                xm[4 * q + kk] = (p >= 0 ? pm_s[pc] : 0.f) * fmv[4 * q + kk];
            }
        }

        float wA[16], wB[16], wC[16];
#pragma unroll
        for (int r = 0; r < 16; ++r) {
            wA[r] = pemb_w[c0 + r];
            wB[r] = pemb_b[c0 + r] + eemb_b[c0 + r];
            wC[r] = eemb_w[c0 + r];
        }
        float* ob = out + ((size_t)b * CC + c0) * TF;

        // ---- row-major sweep: global gather, float4 CACHED stores ----
#pragma unroll
        for (int r = 0; r < 16; ++r) {
            const float* xr = xb + (size_t)(c0 + r) * TP;
            float* obr = ob + (size_t)r * TF;
            float sA = wA[r], sB = wB[r], sC = wC[r];
#pragma unroll
            for (int q = 0; q < 2; ++q) {
                f32x4 o;
#pragma unroll
                for (int kk = 0; kk < 4; ++kk) {
                    int i = 4 * q + kk;
                    float xv = xr[pcl[i]];
                    float t = __builtin_fmaf(lcv[i], sA, sB);
                    t = __builtin_fmaf(env[i], sC, t);
                    o[kk] = __builtin_fmaf(xv, xm[i], t * fmv[i]);
                }
                *(f32x4*)(obr + q * 1024 + 4 * tid) = o;  // plain store (L2 WC)
            }
        }
    } else {
        // ---------------- GEMV + preds block ----------------
        int jj = sl;  // 0..7, phones [jj*64, jj*64+64)
        __shared__ float r[16 * 64];
        __shared__ int ps[256];
        __shared__ float y_lds[3 * 64];
        __shared__ float pm_lds[64];
        __shared__ short po_win[192];
        __shared__ int wsumg[4];
        int t = jj * 64 + lane;
        float a0 = 0.f, a1 = 0.f, a2 = 0.f, a3 = 0.f;
#pragma unroll 8
        for (int i = 0; i < CC / 4; ++i) {
            int cc = __builtin_amdgcn_readfirstlane(wv + 4 * i);
            float xv = xb[cc * TP + t];
            a0 += xv * pitch_w[cc];
            a1 += xv * pitch_w[CC + cc];
            a2 += xv * enp_w[cc];
            a3 += xv * dur_w[cc];
        }
        r[(0 * 4 + wv) * 64 + lane] = a0;
        r[(1 * 4 + wv) * 64 + lane] = a1;
        r[(2 * 4 + wv) * 64 + lane] = a2;
        r[(3 * 4 + wv) * 64 + lane] = a3;
        int2 d01 = *(const int2*)(duration + b * TP + 2 * tid);
        int d0 = d01.x, d1 = d01.y;
        if (tid < 64) pm_lds[tid] = phone_mask[b * TP + jj * 64 + tid];

        // wave-shuffle scan -> inclusive sums into ps[tid]
        int s = d0 + d1;
        int v = s;
#pragma unroll
        for (int off = 1; off < 64; off <<= 1) {
            int tt = __shfl_up(v, off, 64);
            if (lane >= off) v += tt;
        }
        if (lane == 63) wsumg[wv] = v;
        __syncthreads();  // r[], pm_lds, wsumg ready
        int base = 0;
#pragma unroll
        for (int w = 0; w < 4; ++w) base += (w < wv) ? wsumg[w] : 0;
        ps[tid] = base + v;
        __syncthreads();  // ps visible

        // y reduce: wave wv owns output o=wv
        float a = 0.f;
#pragma unroll
        for (int kk = 0; kk < 4; ++kk) a += r[(wv * 4 + kk) * 64 + lane];
        if (wv == 3)
            ldp[b * TP + t] = (a + dur_b[0]) * pm_lds[lane];
        else
            y_lds[wv * 64 + lane] = a;
        // window scatter by the 32 owning pair-threads
        int base_lo = (jj > 0) ? imin(ps[jj * 32 - 1], TF) : 0;
        int base_hi = imin(ps[(jj + 1) * 32 - 1], TF);
        if (tid >= jj * 32 && tid < (jj + 1) * 32) {
            int excl = tid ? ps[tid - 1] : 0;
            int e0 = imin(excl + d0, TF);
            int e1 = imin(excl + d0 + d1, TF);
            for (int f = imin(excl, TF); f < e0; ++f) po_win[f - base_lo] = (short)(2 * tid - jj * 64);
            for (int f = e0; f < e1; ++f) po_win[f - base_lo] = (short)(2 * tid + 1 - jj * 64);
        }
        int total = imin(ps[255], TF);
        __syncthreads();
        int win = base_hi - base_lo;
        for (int idx = tid; idx < win; idx += 256) {
            int f = base_lo + idx;
            int p = po_win[idx];
            float fm = frame_mask[b * TF + f];
            float xm = pm_lds[p] * fm;
            lcp[b * TF + f] = (y_lds[p] * xm + pitch_b[0]) * fm;
            vup[b * TF + f] = (y_lds[64 + p] * xm + pitch_b[1]) * fm;
            epp[b * TF + f] = (y_lds[128 + p] * xm + enp_b[0]) * fm;
        }
        if (jj == 7) {
            for (int f = total + tid; f < TF; f += 256) {
                float fm = frame_mask[b * TF + f];
                lcp[b * TF + f] = pitch_b[0] * fm;
                vup[b * TF + f] = pitch_b[1] * fm;
                epp[b * TF + f] = enp_b[0] * fm;
            }
        }
    }
}

extern "C" void kernel_launch(void* const* d_in, const int* in_sizes, int n_in,
                              void* d_out, int out_size, void* d_ws, size_t ws_size,
                              hipStream_t stream) {
    const float* x          = (const float*)d_in[0];
    const float* phone_mask = (const float*)d_in[1];
    const float* frame_mask = (const float*)d_in[2];
    const int*   duration   = (const int*)d_in[3];
    const float* log_cf0    = (const float*)d_in[4];
    const float* energy     = (const float*)d_in[6];
    const float* dur_w      = (const float*)d_in[7];
    const float* dur_b      = (const float*)d_in[8];
    const float* pitch_w    = (const float*)d_in[9];
    const float* pitch_b    = (const float*)d_in[10];
    const float* pemb_w     = (const float*)d_in[11];
    const float* pemb_b     = (const float*)d_in[12];
    const float* enp_w      = (const float*)d_in[13];
    const float* enp_b      = (const float*)d_in[14];
    const float* eemb_w     = (const float*)d_in[15];
    const float* eemb_b     = (const float*)d_in[16];

    float* out = (float*)d_out;
    float* ldp = out + (size_t)BB * CC * TF;
    float* lcp = ldp + (size_t)BB * TP;
    float* vup = lcp + (size_t)BB * TF;
    float* epp = vup + (size_t)BB * TF;

    mono_kernel<<<dim3(1024), dim3(256), 0, stream>>>(
        x, phone_mask, frame_mask, duration, log_cf0, energy, dur_w, dur_b,
        pitch_w, pitch_b, pemb_w, pemb_b, enp_w, enp_b, eemb_w, eemb_b,
        out, ldp, lcp, vup, epp);
}

// Round 11
// 29.166 us; speedup vs baseline: 1.0198x; 1.0198x over previous
//
#include <hip/hip_runtime.h>

#define BB 32
#define CC 384
#define TP 512
#define TF 2048

typedef float f32x4 __attribute__((ext_vector_type(4)));

__device__ __forceinline__ int imax(int a, int b) { return a > b ? a : b; }
__device__ __forceinline__ int imin(int a, int b) { return a < b ? a : b; }

// FINAL (best measured variant, = R6 at 29.18 us):
// One kernel, no inter-block dependencies. Grid (32, BB), 256 threads.
//  j<24 : stream 16 c-rows x 2048 frames of out; wave-shuffle scan (2 barriers);
//         direct global gather of x (no LDS staging; 64 consecutive frames map
//         to ~43 consecutive phones -> ~2-3 cache lines per wave-instr, L1/L2
//         resident); float4 nontemporal stores (1KB contiguous per wave-instr).
//  j>=24: phone-space GEMV (y kept in LDS) + ldp + frame preds for this
//         block's contiguous frame window; jj==7 also writes the tail.
// Session ledger (11 experiments): staging removal -2.1us, shuffle-scan -0.4us;
// bank conflicts / occupancy(up&down) / CU+XCD balance / write order / store
// width / nt-vs-cached all null or regressive. Effective 4.35 TB/s on a
// ~16%read/84%write gather+stream mix = practical roofline for this pattern.
__global__ __launch_bounds__(256, 4) void mono_kernel(
    const float* __restrict__ x, const float* __restrict__ phone_mask,
    const float* __restrict__ frame_mask, const int* __restrict__ duration,
    const float* __restrict__ log_cf0, const float* __restrict__ energy,
    const float* __restrict__ dur_w, const float* __restrict__ dur_b,
    const float* __restrict__ pitch_w, const float* __restrict__ pitch_b,
    const float* __restrict__ pemb_w, const float* __restrict__ pemb_b,
    const float* __restrict__ enp_w, const float* __restrict__ enp_b,
    const float* __restrict__ eemb_w, const float* __restrict__ eemb_b,
    float* __restrict__ out, float* __restrict__ ldp, float* __restrict__ lcp,
    float* __restrict__ vup, float* __restrict__ epp) {
    int b = blockIdx.y;
    int j = blockIdx.x;
    int tid = threadIdx.x;
    int lane = tid & 63;
    int wv = tid >> 6;  // 0..3
    const float* xb = x + (size_t)b * CC * TP;

    if (j < 24) {
        // ---------------- stream block ----------------
        __shared__ short po16[TF];  // 4 KB frame->phone
        __shared__ float pm_s[TP];  // 2 KB phone_mask row
        __shared__ int wsum[4];     // per-wave scan totals
        int c0 = __builtin_amdgcn_readfirstlane(j * 16);

        // ---- early independent loads (latency hides under scan) ----
        const float* fm_b = frame_mask + (size_t)b * TF;
        const float* lc_b = log_cf0 + (size_t)b * TF;
        const float* en_b = energy + (size_t)b * TF;
        float fmv[8], lcv[8], env[8];
#pragma unroll
        for (int q = 0; q < 2; ++q) {
            int f = q * 1024 + 4 * tid;
            float4 fm4 = *(const float4*)(fm_b + f);
            float4 lc4 = *(const float4*)(lc_b + f);
            float4 en4 = *(const float4*)(en_b + f);
            fmv[4 * q + 0] = fm4.x; fmv[4 * q + 1] = fm4.y; fmv[4 * q + 2] = fm4.z; fmv[4 * q + 3] = fm4.w;
            lcv[4 * q + 0] = lc4.x; lcv[4 * q + 1] = lc4.y; lcv[4 * q + 2] = lc4.z; lcv[4 * q + 3] = lc4.w;
            env[4 * q + 0] = en4.x; env[4 * q + 1] = en4.y; env[4 * q + 2] = en4.z; env[4 * q + 3] = en4.w;
        }
        pm_s[tid] = phone_mask[b * TP + tid];
        pm_s[tid + 256] = phone_mask[b * TP + tid + 256];
        int2 d01 = *(const int2*)(duration + b * TP + 2 * tid);
        int d0 = d01.x, d1 = d01.y;
#pragma unroll
        for (int h = 0; h < 4; ++h) ((int*)po16)[tid + 256 * h] = -1;  // two -1 shorts

        // ---- wave-shuffle inclusive scan of pair sums ----
        int s = d0 + d1;
        int v = s;
#pragma unroll
        for (int off = 1; off < 64; off <<= 1) {
            int t = __shfl_up(v, off, 64);
            if (lane >= off) v += t;
        }
        if (lane == 63) wsum[wv] = v;
        __syncthreads();  // wsum + po16 init + pm_s ready
        int base = 0;
#pragma unroll
        for (int w = 0; w < 4; ++w) base += (w < wv) ? wsum[w] : 0;
        int excl = base + v - s;

        int e0 = imin(excl + d0, TF);
        int e1 = imin(excl + d0 + d1, TF);
        for (int f = imin(excl, TF); f < e0; ++f) po16[f] = (short)(2 * tid);
        for (int f = e0; f < e1; ++f) po16[f] = (short)(2 * tid + 1);
        __syncthreads();

        // ---- po16-dependent register cache: gather index + combined mask ----
        int pcl[8];
        float xm[8];
#pragma unroll
        for (int q = 0; q < 2; ++q) {
            short4 p4 = *(const short4*)(po16 + q * 1024 + 4 * tid);
            short pk[4] = {p4.x, p4.y, p4.z, p4.w};
#pragma unroll
            for (int k = 0; k < 4; ++k) {
                int p = pk[k];
                int pc = imax(p, 0);
                pcl[4 * q + k] = pc;
                xm[4 * q + k] = (p >= 0 ? pm_s[pc] : 0.f) * fmv[4 * q + k];
            }
        }

        float wA[16], wB[16], wC[16];
#pragma unroll
        for (int r = 0; r < 16; ++r) {
            wA[r] = pemb_w[c0 + r];
            wB[r] = pemb_b[c0 + r] + eemb_b[c0 + r];
            wC[r] = eemb_w[c0 + r];
        }
        float* ob = out + ((size_t)b * CC + c0) * TF;

        // ---- row-major sweep: global gather, float4 nt stores (1KB/wave-instr) ----
#pragma unroll
        for (int r = 0; r < 16; ++r) {
            const float* xr = xb + (size_t)(c0 + r) * TP;
            float* obr = ob + (size_t)r * TF;
            float sA = wA[r], sB = wB[r], sC = wC[r];
#pragma unroll
            for (int q = 0; q < 2; ++q) {
                f32x4 o;
#pragma unroll
                for (int k = 0; k < 4; ++k) {
                    int i = 4 * q + k;
                    float xv = xr[pcl[i]];
                    float t = __builtin_fmaf(lcv[i], sA, sB);
                    t = __builtin_fmaf(env[i], sC, t);
                    o[k] = __builtin_fmaf(xv, xm[i], t * fmv[i]);
                }
                __builtin_nontemporal_store(o, (f32x4*)(obr + q * 1024 + 4 * tid));
            }
        }
    } else {
        // ---------------- GEMV + preds block ----------------
        int jj = j - 24;  // 0..7, phones [jj*64, jj*64+64)
        __shared__ float r[16 * 64];
        __shared__ int ps[256];
        __shared__ float y_lds[3 * 64];
        __shared__ float pm_lds[64];
        __shared__ short po_win[192];
        __shared__ int wsumg[4];
        int t = jj * 64 + lane;
        float a0 = 0.f, a1 = 0.f, a2 = 0.f, a3 = 0.f;
#pragma unroll 8
        for (int i = 0; i < CC / 4; ++i) {
            int c = __builtin_amdgcn_readfirstlane(wv + 4 * i);
            float xv = xb[c * TP + t];
            a0 += xv * pitch_w[c];
            a1 += xv * pitch_w[CC + c];
            a2 += xv * enp_w[c];
            a3 += xv * dur_w[c];
        }
        r[(0 * 4 + wv) * 64 + lane] = a0;
        r[(1 * 4 + wv) * 64 + lane] = a1;
        r[(2 * 4 + wv) * 64 + lane] = a2;
        r[(3 * 4 + wv) * 64 + lane] = a3;
        int2 d01 = *(const int2*)(duration + b * TP + 2 * tid);
        int d0 = d01.x, d1 = d01.y;
        if (tid < 64) pm_lds[tid] = phone_mask[b * TP + jj * 64 + tid];

        // wave-shuffle scan -> inclusive sums into ps[tid]
        int s = d0 + d1;
        int v = s;
#pragma unroll
        for (int off = 1; off < 64; off <<= 1) {
            int tt = __shfl_up(v, off, 64);
            if (lane >= off) v += tt;
        }
        if (lane == 63) wsumg[wv] = v;
        __syncthreads();  // r[], pm_lds, wsumg ready
        int base = 0;
#pragma unroll
        for (int w = 0; w < 4; ++w) base += (w < wv) ? wsumg[w] : 0;
        ps[tid] = base + v;
        __syncthreads();  // ps visible

        // y reduce: wave wv owns output o=wv
        float a = 0.f;
#pragma unroll
        for (int k = 0; k < 4; ++k) a += r[(wv * 4 + k) * 64 + lane];
        if (wv == 3)
            ldp[b * TP + t] = (a + dur_b[0]) * pm_lds[lane];
        else
            y_lds[wv * 64 + lane] = a;
        // window scatter by the 32 owning pair-threads
        int base_lo = (jj > 0) ? imin(ps[jj * 32 - 1], TF) : 0;
        int base_hi = imin(ps[(jj + 1) * 32 - 1], TF);
        if (tid >= jj * 32 && tid < (jj + 1) * 32) {
            int excl = tid ? ps[tid - 1] : 0;
            int e0 = imin(excl + d0, TF);
            int e1 = imin(excl + d0 + d1, TF);
            for (int f = imin(excl, TF); f < e0; ++f) po_win[f - base_lo] = (short)(2 * tid - jj * 64);
            for (int f = e0; f < e1; ++f) po_win[f - base_lo] = (short)(2 * tid + 1 - jj * 64);
        }
        int total = imin(ps[255], TF);
        __syncthreads();
        int win = base_hi - base_lo;
        for (int idx = tid; idx < win; idx += 256) {
            int f = base_lo + idx;
            int p = po_win[idx];
            float fm = frame_mask[b * TF + f];
            float xm = pm_lds[p] * fm;
            lcp[b * TF + f] = (y_lds[p] * xm + pitch_b[0]) * fm;
            vup[b * TF + f] = (y_lds[64 + p] * xm + pitch_b[1]) * fm;
            epp[b * TF + f] = (y_lds[128 + p] * xm + enp_b[0]) * fm;
        }
        if (jj == 7) {
            for (int f = total + tid; f < TF; f += 256) {
                float fm = frame_mask[b * TF + f];
                lcp[b * TF + f] = pitch_b[0] * fm;
                vup[b * TF + f] = pitch_b[1] * fm;
                epp[b * TF + f] = enp_b[0] * fm;
            }
        }
    }
}

extern "C" void kernel_launch(void* const* d_in, const int* in_sizes, int n_in,
                              void* d_out, int out_size, void* d_ws, size_t ws_size,
                              hipStream_t stream) {
    const float* x          = (const float*)d_in[0];
    const float* phone_mask = (const float*)d_in[1];
    const float* frame_mask = (const float*)d_in[2];
    const int*   duration   = (const int*)d_in[3];
    const float* log_cf0    = (const float*)d_in[4];
    const float* energy     = (const float*)d_in[6];
    const float* dur_w      = (const float*)d_in[7];
    const float* dur_b      = (const float*)d_in[8];
    const float* pitch_w    = (const float*)d_in[9];
    const float* pitch_b    = (const float*)d_in[10];
    const float* pemb_w     = (const float*)d_in[11];
    const float* pemb_b     = (const float*)d_in[12];
    const float* enp_w      = (const float*)d_in[13];
    const float* enp_b      = (const float*)d_in[14];
    const float* eemb_w     = (const float*)d_in[15];
    const float* eemb_b     = (const float*)d_in[16];

    float* out = (float*)d_out;
    float* ldp = out + (size_t)BB * CC * TF;
    float* lcp = ldp + (size_t)BB * TP;
    float* vup = lcp + (size_t)BB * TF;
    float* epp = vup + (size_t)BB * TF;

    mono_kernel<<<dim3(32, BB), dim3(256), 0, stream>>>(
        x, phone_mask, frame_mask, duration, log_cf0, energy, dur_w, dur_b,
        pitch_w, pitch_b, pemb_w, pemb_b, enp_w, enp_b, eemb_w, eemb_b,
        out, ldp, lcp, vup, epp);
}